// Round 5
// baseline (1627.763 us; speedup 1.0000x reference)
//
#include <hip/hip_runtime.h>

typedef unsigned int u32;
typedef unsigned short ushort_t;

typedef __attribute__((ext_vector_type(8)))  short bf16x8;   // 8 bf16 = 4 VGPR
typedef __attribute__((ext_vector_type(16))) float f32x16;   // 32x32 MFMA acc

#define ENS 10
#define NU 256
#define NHID 7
#define IN_DIM 6
#define OUT_DIM 201
#define BATCH 16384

// ---- 32x32x16 bf16 fragment layouts ----
// A: lane l holds m = l&31,  k = (l>>5)*8 + j   (j=0..7)
// B: lane l holds n = l&31,  k = (l>>5)*8 + j
// C/D: lane l holds col = l&31, row = (r&3) + 8*(r>>2) + 4*(l>>5)  (r=0..15)

// fragment-array sizes in ushort (bf16) elements, per plane
#define WH_PER 65536                  // per (layer,ens): 16 s * 8 ctg * 64 * 8
#define WH_TOT (NHID * ENS * WH_PER)  // 4,587,520
#define W0_PER 4096                   // per ens: 8 ctg * 64 * 8 (K pad 6->16)
#define W0_TOT (ENS * W0_PER)
#define WF_PER 57344                  // per ens: 16 s * 7 ctg * 64 * 8 (N pad 201->224)
#define WF_TOT (ENS * WF_PER)
#define X_TOT ((BATCH / 32) * 64 * 8) // 262,144 (K pad 6->16)

// ws layout (ushort units); total ~20.8 MiB
#define O_WHH 0
#define O_WHL (O_WHH + WH_TOT)
#define O_W0H (O_WHL + WH_TOT)
#define O_W0L (O_W0H + W0_TOT)
#define O_WFH (O_W0L + W0_TOT)
#define O_WFL (O_WFH + WF_TOT)
#define O_XH  (O_WFL + WF_TOT)
#define O_XL  (O_XH + X_TOT)

#define RS 264   // act plane row stride (ushort); 528B row: b128-aligned per lane

__device__ __forceinline__ u32 bf16_rne(float f) {
    u32 u = __float_as_uint(f);
    return (u + 0x7FFFu + ((u >> 16) & 1u)) >> 16;
}
__device__ __forceinline__ void split2(float f, u32& h, u32& l) {
    h = bf16_rne(f);
    float fh = __uint_as_float(h << 16);
    l = bf16_rne(f - fh);
}

// ---------------- prep kernels: fp32 -> hi/lo bf16, B/A-frag-linear ----------------

__global__ __launch_bounds__(256) void prep_wh(const float* __restrict__ Wh,
                                               ushort_t* __restrict__ dH, ushort_t* __restrict__ dL) {
    int i = blockIdx.x * 256 + threadIdx.x;
    if (i >= WH_TOT) return;
    int j = i & 7, l = (i >> 3) & 63, ctg = (i >> 9) & 7, s = (i >> 12) & 15, le = i >> 16;
    int k = s * 16 + ((l >> 5) << 3) + j;
    int n = ctg * 32 + (l & 31);
    float v = Wh[(size_t)le * 65536 + k * 256 + n];
    u32 h, lo; split2(v, h, lo);
    dH[i] = (ushort_t)h; dL[i] = (ushort_t)lo;
}

__global__ __launch_bounds__(256) void prep_w0(const float* __restrict__ W0,
                                               ushort_t* __restrict__ dH, ushort_t* __restrict__ dL) {
    int i = blockIdx.x * 256 + threadIdx.x;
    if (i >= W0_TOT) return;
    int j = i & 7, l = (i >> 3) & 63, ctg = (i >> 9) & 7, e = i >> 12;
    int k = ((l >> 5) << 3) + j;       // 0..15, valid < 6
    int n = ctg * 32 + (l & 31);
    float v = (k < IN_DIM) ? W0[(e * IN_DIM + k) * 256 + n] : 0.0f;
    u32 h, lo; split2(v, h, lo);
    dH[i] = (ushort_t)h; dL[i] = (ushort_t)lo;
}

__global__ __launch_bounds__(256) void prep_wf(const float* __restrict__ Wf,
                                               ushort_t* __restrict__ dH, ushort_t* __restrict__ dL) {
    int i = blockIdx.x * 256 + threadIdx.x;
    if (i >= WF_TOT) return;
    int e = i / WF_PER;
    int idx = i - e * WF_PER;
    int j = idx & 7, l = (idx >> 3) & 63, g = idx >> 9;  // g = s*7+ct, 0..111
    int s = g / 7, ct = g - s * 7;
    int k = s * 16 + ((l >> 5) << 3) + j;
    int n = ct * 32 + (l & 31);
    float v = (n < OUT_DIM) ? Wf[((size_t)e * 256 + k) * OUT_DIM + n] : 0.0f;
    u32 h, lo; split2(v, h, lo);
    dH[i] = (ushort_t)h; dL[i] = (ushort_t)lo;
}

__global__ __launch_bounds__(256) void prep_x(const float* __restrict__ x,
                                              ushort_t* __restrict__ dH, ushort_t* __restrict__ dL) {
    int i = blockIdx.x * 256 + threadIdx.x;
    if (i >= X_TOT) return;
    int j = i & 7, l = (i >> 3) & 63, rt = i >> 9;   // rt = 0..511
    int row = rt * 32 + (l & 31);
    int k = ((l >> 5) << 3) + j;
    float v = (k < IN_DIM) ? x[row * IN_DIM + k] : 0.0f;
    u32 h, lo; split2(v, h, lo);
    dH[i] = (ushort_t)h; dL[i] = (ushort_t)lo;
}

__global__ __launch_bounds__(256) void zero_out_kernel(float* __restrict__ out, int n) {
    int i = blockIdx.x * blockDim.x + threadIdx.x;
    int stride = gridDim.x * blockDim.x;
    for (; i < n; i += stride) out[i] = 0.0f;
}

#define MFMA32(A, B, C) __builtin_amdgcn_mfma_f32_32x32x16_bf16((A), (B), (C), 0, 0, 0)

// ---------------- fused MLP: 32x32x16 split-bf16, pipelined A+B ----------------
// grid 5120 (XCD-swizzled); 256 threads = 4 waves; wave cg owns cols
// [cg*64, cg*64+64) (ct tiles ctg0=2cg, 2cg+1) of this WG's 32 batch rows.
// LDS 33.8 KB -> 4 WG/CU (16 waves/CU), 4 independent barrier domains.
__global__ __launch_bounds__(256, 4)
void mlp_mfma(const ushort_t* __restrict__ wsU,
              const float* __restrict__ b0g, const float* __restrict__ bhg,
              const float* __restrict__ bfg, float* __restrict__ out) {
    __shared__ ushort_t actH[32 * RS];   // 16,896 B
    __shared__ ushort_t actL[32 * RS];   // 16,896 B

    const int tid  = threadIdx.x;
    const int lane = tid & 63;
    const int cg   = tid >> 6;        // wave 0..3
    const int l31  = lane & 31;
    const int lh   = lane >> 5;       // 0..1
    const int ctg0 = cg * 2;

    // XCD-aware bijective swizzle: 5120 WGs, 8 XCDs, 640/XCD
    const int bid  = blockIdx.x;
    const int work = (bid & 7) * 640 + (bid >> 3);
    const int e    = work >> 9;       // ensemble 0..9
    const int rb   = work & 511;      // row block 0..511
    const int rowWG = rb * 32;

    const size_t lo8 = (size_t)lane * 8;
    const ushort_t* arH = actH + l31 * RS;
    const ushort_t* arL = actL + l31 * RS;
    const int rowb = lh * 4;          // epilogue row base

    f32x16 acc0, acc1;
    bf16x8 Bc0, Bc1, Bc2, Bc3;        // current B: [ctg0 hi, ctg0 lo, ctg0+1 hi, ctg0+1 lo]
    bf16x8 aH, aL;

    // ================ layer 0 (K padded 6->16, single k-step) ================
    {
        const ushort_t* B0H = wsU + O_W0H + (size_t)e * W0_PER;
        const ushort_t* B0L = wsU + O_W0L + (size_t)e * W0_PER;
        Bc0 = *(const bf16x8*)(B0H + (size_t)ctg0 * 512 + lo8);
        Bc1 = *(const bf16x8*)(B0L + (size_t)ctg0 * 512 + lo8);
        Bc2 = *(const bf16x8*)(B0H + (size_t)(ctg0 + 1) * 512 + lo8);
        Bc3 = *(const bf16x8*)(B0L + (size_t)(ctg0 + 1) * 512 + lo8);
        size_t xoff = ((size_t)rb * 64 + lane) * 8;
        aH = *(const bf16x8*)(wsU + O_XH + xoff);
        aL = *(const bf16x8*)(wsU + O_XL + xoff);
        // prefetch hidden layer 0, s=0 B
        const ushort_t* BH0 = wsU + O_WHH + (size_t)e * WH_PER;
        const ushort_t* BL0 = wsU + O_WHL + (size_t)e * WH_PER;
        bf16x8 Bn0 = *(const bf16x8*)(BH0 + (size_t)ctg0 * 512 + lo8);
        bf16x8 Bn1 = *(const bf16x8*)(BL0 + (size_t)ctg0 * 512 + lo8);
        bf16x8 Bn2 = *(const bf16x8*)(BH0 + (size_t)(ctg0 + 1) * 512 + lo8);
        bf16x8 Bn3 = *(const bf16x8*)(BL0 + (size_t)(ctg0 + 1) * 512 + lo8);
        __builtin_amdgcn_sched_barrier(0);

        f32x16 z = 0.0f;
        acc0 = z; acc1 = z;
        acc0 = MFMA32(aH, Bc0, acc0);
        acc0 = MFMA32(aL, Bc0, acc0);
        acc0 = MFMA32(aH, Bc1, acc0);
        acc1 = MFMA32(aH, Bc2, acc1);
        acc1 = MFMA32(aL, Bc2, acc1);
        acc1 = MFMA32(aH, Bc3, acc1);

        float bv0 = b0g[e * NU + ctg0 * 32 + l31];
        float bv1 = b0g[e * NU + (ctg0 + 1) * 32 + l31];
        int colA = ctg0 * 32 + l31, colB = colA + 32;
#pragma unroll
        for (int r = 0; r < 16; ++r) {
            int row = rowb + (r & 3) + 8 * (r >> 2);
            float f0 = fmaxf(acc0[r] + bv0, 0.0f);
            float f1 = fmaxf(acc1[r] + bv1, 0.0f);
            u32 h0, q0, h1, q1;
            split2(f0, h0, q0); split2(f1, h1, q1);
            actH[row * RS + colA] = (ushort_t)h0; actL[row * RS + colA] = (ushort_t)q0;
            actH[row * RS + colB] = (ushort_t)h1; actL[row * RS + colB] = (ushort_t)q1;
        }
        Bc0 = Bn0; Bc1 = Bn1; Bc2 = Bn2; Bc3 = Bn3;
        __syncthreads();
    }

    // ================ 7 hidden layers (K=256, 16 k-steps, A+B pipelined) ================
    const ushort_t* BH = wsU + O_WHH + (size_t)e * WH_PER;
    const ushort_t* BL = wsU + O_WHL + (size_t)e * WH_PER;
#pragma unroll 1
    for (int L = 0; L < NHID; ++L) {
        float bv0 = bhg[(size_t)(L * ENS + e) * NU + ctg0 * 32 + l31];
        float bv1 = bhg[(size_t)(L * ENS + e) * NU + (ctg0 + 1) * 32 + l31];
        f32x16 z = 0.0f;
        acc0 = z; acc1 = z;
        // A for s=0
        aH = *(const bf16x8*)(arH + lh * 8);
        aL = *(const bf16x8*)(arL + lh * 8);

#pragma unroll
        for (int s = 0; s < 16; ++s) {
            bf16x8 aHn, aLn, Bn0, Bn1, Bn2, Bn3;
            if (s < 15) {
                int kn = (s + 1) * 16 + lh * 8;
                aHn = *(const bf16x8*)(arH + kn);
                aLn = *(const bf16x8*)(arL + kn);
                const ushort_t* ph = BH + (size_t)((s + 1) * 8 + ctg0) * 512;
                const ushort_t* pl = BL + (size_t)((s + 1) * 8 + ctg0) * 512;
                Bn0 = *(const bf16x8*)(ph + lo8);
                Bn1 = *(const bf16x8*)(pl + lo8);
                Bn2 = *(const bf16x8*)(ph + 512 + lo8);
                Bn3 = *(const bf16x8*)(pl + 512 + lo8);
            }
            __builtin_amdgcn_sched_barrier(0);
            acc0 = MFMA32(aH, Bc0, acc0);
            acc0 = MFMA32(aL, Bc0, acc0);
            acc0 = MFMA32(aH, Bc1, acc0);
            acc1 = MFMA32(aH, Bc2, acc1);
            acc1 = MFMA32(aL, Bc2, acc1);
            acc1 = MFMA32(aH, Bc3, acc1);
            if (s < 15) {
                aH = aHn; aL = aLn;
                Bc0 = Bn0; Bc1 = Bn1; Bc2 = Bn2; Bc3 = Bn3;
            }
        }

        // prefetch next layer's s=0 B (or final layer's) before the barriers
        if (L < NHID - 1) {
            const ushort_t* nh = BH + (size_t)ENS * WH_PER;
            const ushort_t* nl = BL + (size_t)ENS * WH_PER;
            Bc0 = *(const bf16x8*)(nh + (size_t)ctg0 * 512 + lo8);
            Bc1 = *(const bf16x8*)(nl + (size_t)ctg0 * 512 + lo8);
            Bc2 = *(const bf16x8*)(nh + (size_t)(ctg0 + 1) * 512 + lo8);
            Bc3 = *(const bf16x8*)(nl + (size_t)(ctg0 + 1) * 512 + lo8);
        } else {
            const ushort_t* fh = wsU + O_WFH + (size_t)e * WF_PER;
            const ushort_t* fl = wsU + O_WFL + (size_t)e * WF_PER;
            int c0 = ctg0, c1 = (ctg0 + 1 > 6) ? 6 : ctg0 + 1;
            if (c0 > 6) c0 = 6;
            Bc0 = *(const bf16x8*)(fh + (size_t)c0 * 512 + lo8);
            Bc1 = *(const bf16x8*)(fl + (size_t)c0 * 512 + lo8);
            Bc2 = *(const bf16x8*)(fh + (size_t)c1 * 512 + lo8);
            Bc3 = *(const bf16x8*)(fl + (size_t)c1 * 512 + lo8);
        }

        __syncthreads();   // all act reads of this layer done before overwrite
        int colA = ctg0 * 32 + l31, colB = colA + 32;
#pragma unroll
        for (int r = 0; r < 16; ++r) {
            int row = rowb + (r & 3) + 8 * (r >> 2);
            float f0 = fmaxf(acc0[r] + bv0, 0.0f);
            float f1 = fmaxf(acc1[r] + bv1, 0.0f);
            u32 h0, q0, h1, q1;
            split2(f0, h0, q0); split2(f1, h1, q1);
            actH[row * RS + colA] = (ushort_t)h0; actL[row * RS + colA] = (ushort_t)q0;
            actH[row * RS + colB] = (ushort_t)h1; actL[row * RS + colB] = (ushort_t)q1;
        }
        __syncthreads();
        BH += (size_t)ENS * WH_PER;
        BL += (size_t)ENS * WH_PER;
    }

    // ================ final layer (N padded 201->224 = 7 ct-tiles) ================
    {
        const ushort_t* FH = wsU + O_WFH + (size_t)e * WF_PER;
        const ushort_t* FL = wsU + O_WFL + (size_t)e * WF_PER;
        int c0 = (ctg0 > 6) ? 6 : ctg0;
        int c1 = (ctg0 + 1 > 6) ? 6 : ctg0 + 1;
        f32x16 z = 0.0f;
        acc0 = z; acc1 = z;
        aH = *(const bf16x8*)(arH + lh * 8);
        aL = *(const bf16x8*)(arL + lh * 8);

#pragma unroll
        for (int s = 0; s < 16; ++s) {
            bf16x8 aHn, aLn, Bn0, Bn1, Bn2, Bn3;
            if (s < 15) {
                int kn = (s + 1) * 16 + lh * 8;
                aHn = *(const bf16x8*)(arH + kn);
                aLn = *(const bf16x8*)(arL + kn);
                Bn0 = *(const bf16x8*)(FH + (size_t)((s + 1) * 7 + c0) * 512 + lo8);
                Bn1 = *(const bf16x8*)(FL + (size_t)((s + 1) * 7 + c0) * 512 + lo8);
                Bn2 = *(const bf16x8*)(FH + (size_t)((s + 1) * 7 + c1) * 512 + lo8);
                Bn3 = *(const bf16x8*)(FL + (size_t)((s + 1) * 7 + c1) * 512 + lo8);
            }
            __builtin_amdgcn_sched_barrier(0);
            acc0 = MFMA32(aH, Bc0, acc0);
            acc0 = MFMA32(aL, Bc0, acc0);
            acc0 = MFMA32(aH, Bc1, acc0);
            acc1 = MFMA32(aH, Bc2, acc1);
            acc1 = MFMA32(aL, Bc2, acc1);
            acc1 = MFMA32(aH, Bc3, acc1);
            if (s < 15) {
                aH = aHn; aL = aLn;
                Bc0 = Bn0; Bc1 = Bn1; Bc2 = Bn2; Bc3 = Bn3;
            }
        }

        // strided-mean epilogue: out[b][(e*201+o)/10] += 0.1 * (y + bias)
        int o0 = ctg0 * 32 + l31;
        int o1 = (ctg0 + 1) * 32 + l31;
        bool v0 = (o0 < OUT_DIM);
        bool v1 = (ctg0 + 1 < 7) && (o1 < OUT_DIM);
        float bf0 = v0 ? bfg[e * OUT_DIM + o0] : 0.0f;
        float bf1 = v1 ? bfg[e * OUT_DIM + o1] : 0.0f;
        int jo0 = (e * OUT_DIM + o0) / 10;
        int jo1 = (e * OUT_DIM + o1) / 10;
#pragma unroll
        for (int r = 0; r < 16; ++r) {
            int rowg = rowWG + rowb + (r & 3) + 8 * (r >> 2);
            if (v0) atomicAdd(out + (size_t)rowg * OUT_DIM + jo0, 0.1f * (acc0[r] + bf0));
            if (v1) atomicAdd(out + (size_t)rowg * OUT_DIM + jo1, 0.1f * (acc1[r] + bf1));
        }
    }
}

extern "C" void kernel_launch(void* const* d_in, const int* in_sizes, int n_in,
                              void* d_out, int out_size, void* d_ws, size_t ws_size,
                              hipStream_t stream) {
    const float* x  = (const float*)d_in[0];
    const float* W0 = (const float*)d_in[1];
    const float* b0 = (const float*)d_in[2];
    const float* Wh = (const float*)d_in[3];
    const float* bh = (const float*)d_in[4];
    const float* Wf = (const float*)d_in[5];
    const float* bf = (const float*)d_in[6];
    float* out = (float*)d_out;
    ushort_t* ws = (ushort_t*)d_ws;   // needs ~21 MB

    prep_wh<<<(WH_TOT + 255) / 256, 256, 0, stream>>>(Wh, ws + O_WHH, ws + O_WHL);
    prep_w0<<<(W0_TOT + 255) / 256, 256, 0, stream>>>(W0, ws + O_W0H, ws + O_W0L);
    prep_wf<<<(WF_TOT + 255) / 256, 256, 0, stream>>>(Wf, ws + O_WFH, ws + O_WFL);
    prep_x <<<(X_TOT  + 255) / 256, 256, 0, stream>>>(x,  ws + O_XH,  ws + O_XL);
    zero_out_kernel<<<2048, 256, 0, stream>>>(out, out_size);

    mlp_mfma<<<dim3(BATCH / 32 * ENS), 256, 0, stream>>>(ws, b0, bh, bf, out);
}